// Round 7
// baseline (14154.790 us; speedup 1.0000x reference)
//
#include <hip/hip_runtime.h>

// ESN forward, teacher-forced: s[t] = tanh(w@s[t-1] + w_in@in[t] + w_fb@out[t-1]) + 1e-3*(nu[t]-0.5)
// Persistent kernel, 256 blocks x 256 threads, 8 rows/block, W in LDS (64KB).
//
// Round-7: R5 structure + ONE change: software-pipelined 2-bank polling.
// Evidence: R6 falsified op-throughput saturation (halving pollers hurt);
// FETCH arithmetic shows poll traffic ~0.2 lines/cy << fabric service rate
// => latency-bound. R5's poll serialized sweeps: 8 loads -> wait-all ->
// min-check -> sleep(64cy) -> reissue, sampling freshness every ~700-900cy.
// Two in-flight banks sample every ~RTT/2 and drop the sleep from the fast
// path (backoff only after 6 failed check-rounds, tail insurance).
//
// Kept from R5 (8.09ms): W in LDS [rr][cc][tid][j] (0 bank conflicts), pre-poll
// ds_read prefetch + asm fence (lgkmcnt rides out the poll's vmcnt), {fp32,tag}
// fused 8B agent-scope words double-buffered by parity, strided ownership,
// post-detect FMA, one barrier/step, fast tanh (exp2+rcp).

#define N_RES   2048
#define N_IN    64
#define N_OUT   32
#define T_STEPS 4096
#define NOISEC  0.001f
#define NBLK    256
#define NTHR    256
#define RPB     8     // rows per block
#define CPT     8     // state words (cols) per thread, stride NTHR

typedef float f32x4 __attribute__((ext_vector_type(4)));

__device__ __forceinline__ float fast_tanh(float x) {
    // tanh(x) = 1 - 2/(e^{2x}+1);  e^{2x} = exp2(2*log2(e)*x)
    const float e = __builtin_amdgcn_exp2f(2.8853900818f * x);
    return fmaf(-2.f, __builtin_amdgcn_rcpf(e + 1.f), 1.f);
}

__global__ void esn_init(unsigned long long* __restrict__ slots) {
    const int i = blockIdx.x * blockDim.x + threadIdx.x;
    if (i < 2 * N_RES)
        __hip_atomic_store(slots + i, 0ull, __ATOMIC_RELAXED, __HIP_MEMORY_SCOPE_AGENT);
}

__global__ __launch_bounds__(NTHR, 1)
void esn_run(const float* __restrict__ inputs,    // T x 64
             const float* __restrict__ outputs,   // T x 32
             const float* __restrict__ w,         // 2048 x 2048
             const float* __restrict__ w_in,      // 2048 x 64
             const float* __restrict__ w_feedb,   // 2048 x 32
             const float* __restrict__ out_w,     // 32 x 2048
             const float* __restrict__ out_b,     // 32
             const float* __restrict__ noise_u,   // T x 2048
             float* __restrict__ d_out,           // 32 + 2048
             unsigned long long* __restrict__ slots) { // 2 x 2048 tagged words
    const int tid  = threadIdx.x;
    const int blk  = blockIdx.x;
    const int row0 = blk * RPB;
    const int wav  = tid >> 6;
    const int lan  = tid & 63;

    // [rr][cc][tid][j]: element (row = rr*4+j, col = cc*256+tid). 64KB.
    __shared__ float wlds[2 * 8 * NTHR * 4];
    __shared__ float red[2][4][RPB];

    // ---- one-time: stage my block's 8 W rows into LDS (coalesced reads) ----
    #pragma unroll
    for (int r = 0; r < RPB; ++r)
        #pragma unroll
        for (int cc = 0; cc < 8; ++cc) {
            const float v = w[(size_t)(row0 + r) * N_RES + cc * NTHR + tid];
            wlds[(((r >> 2) * 8 + cc) * NTHR + tid) * 4 + (r & 3)] = v;
        }
    // w_in / w_feedb: one virtual column per thread (tid<96)
    float wex[RPB];
    #pragma unroll
    for (int r = 0; r < RPB; ++r) {
        float v = 0.f;
        if (tid < N_IN)              v = w_in[(row0 + r) * N_IN + tid];
        else if (tid < N_IN + N_OUT) v = w_feedb[(row0 + r) * N_OUT + (tid - N_IN)];
        wex[r] = v;
    }
    __syncthreads();

    for (int t = 1; t < T_STEPS; ++t) {
        const unsigned need = (unsigned)(t - 1);
        const unsigned long long* sl = slots + (size_t)((t - 1) & 1) * N_RES + tid;

        // ---- issue BOTH poll banks immediately (16 outstanding loads) ----
        unsigned long long a[CPT], b[CPT];
        #pragma unroll
        for (int i = 0; i < CPT; ++i)
            a[i] = __hip_atomic_load(sl + i * NTHR, __ATOMIC_RELAXED, __HIP_MEMORY_SCOPE_AGENT);
        #pragma unroll
        for (int i = 0; i < CPT; ++i)
            b[i] = __hip_atomic_load(sl + i * NTHR, __ATOMIC_RELAXED, __HIP_MEMORY_SCOPE_AGENT);

        // off-critical-path operands (overlap with poll latency)
        float xv = 0.f;
        if (tid < N_IN)              xv = inputs[t * N_IN + tid];
        else if (tid < N_IN + N_OUT) xv = outputs[(t - 1) * N_OUT + (tid - N_IN)];
        float nu = 0.f;
        if (tid < RPB) nu = noise_u[(size_t)t * N_RES + row0 + tid];

        // ---- prefetch W fragment from LDS (state-independent) ----
        f32x4 wv[16];
        #pragma unroll
        for (int rr = 0; rr < 2; ++rr)
            #pragma unroll
            for (int cc = 0; cc < 8; ++cc)
                wv[rr * 8 + cc] = *reinterpret_cast<const f32x4*>(
                    &wlds[((rr * 8 + cc) * NTHR + tid) * 4]);

        // fence: nothing above may sink below (ds_reads ride out the poll on
        // the independent lgkmcnt counter)
        asm volatile("" ::: "memory");

        // ---- pipelined 2-bank poll: check A while B is in flight ----
        float sv[CPT];
        unsigned done = 0;
        int tries = 0;
        for (;;) {
            #pragma unroll
            for (int i = 0; i < CPT; ++i)
                if (!((done >> i) & 1) && (unsigned)(a[i] >> 32) >= need) {
                    sv[i] = __uint_as_float((unsigned)(a[i] & 0xffffffffu));
                    done |= 1u << i;
                }
            if (done == 0xffu) break;
            #pragma unroll
            for (int i = 0; i < CPT; ++i)
                if (!((done >> i) & 1))
                    a[i] = __hip_atomic_load(sl + i * NTHR, __ATOMIC_RELAXED, __HIP_MEMORY_SCOPE_AGENT);
            #pragma unroll
            for (int i = 0; i < CPT; ++i)
                if (!((done >> i) & 1) && (unsigned)(b[i] >> 32) >= need) {
                    sv[i] = __uint_as_float((unsigned)(b[i] & 0xffffffffu));
                    done |= 1u << i;
                }
            if (done == 0xffu) break;
            #pragma unroll
            for (int i = 0; i < CPT; ++i)
                if (!((done >> i) & 1))
                    b[i] = __hip_atomic_load(sl + i * NTHR, __ATOMIC_RELAXED, __HIP_MEMORY_SCOPE_AGENT);
            if (++tries > 6) __builtin_amdgcn_s_sleep(1);   // tail backoff only
        }

        // ---- partial dots: 8 rows x my 8 strided cols, W from registers ----
        float acc[RPB];
        #pragma unroll
        for (int r = 0; r < RPB; ++r) acc[r] = 0.f;
        #pragma unroll
        for (int i = 0; i < CPT; ++i) {
            #pragma unroll
            for (int rr = 0; rr < 2; ++rr)
                #pragma unroll
                for (int j = 0; j < 4; ++j)
                    acc[rr * 4 + j] = fmaf(wv[rr * 8 + i][j], sv[i], acc[rr * 4 + j]);
        }
        #pragma unroll
        for (int r = 0; r < RPB; ++r) acc[r] = fmaf(wex[r], xv, acc[r]);

        // ---- wave reduce: halving exchange (1,2,4) then butterfly (8,16,32) ----
        {   const bool s = (lan & 1);
            #pragma unroll
            for (int r = 0; r < 4; ++r) {
                const float send = s ? acc[r] : acc[r + 4];
                const float got  = __shfl_xor(send, 1, 64);
                acc[r] = (s ? acc[r + 4] : acc[r]) + got;
            }
        }
        {   const bool s = (lan >> 1) & 1;
            #pragma unroll
            for (int r = 0; r < 2; ++r) {
                const float send = s ? acc[r] : acc[r + 2];
                const float got  = __shfl_xor(send, 2, 64);
                acc[r] = (s ? acc[r + 2] : acc[r]) + got;
            }
        }
        {   const bool s = (lan >> 2) & 1;
            const float send = s ? acc[0] : acc[1];
            const float got  = __shfl_xor(send, 4, 64);
            acc[0] = (s ? acc[1] : acc[0]) + got;
        }
        #pragma unroll
        for (int m = 8; m < 64; m <<= 1) acc[0] += __shfl_xor(acc[0], m, 64);
        if (lan < 8) {
            const int rb = 4 * (lan & 1) + 2 * ((lan >> 1) & 1) + ((lan >> 2) & 1);
            red[t & 1][wav][rb] = acc[0];
        }
        __syncthreads();

        // ---- wave 0, lanes 0-7: final sum + tanh + single-line publish ----
        if (tid < RPB) {
            const float tot = red[t & 1][0][tid] + red[t & 1][1][tid]
                            + red[t & 1][2][tid] + red[t & 1][3][tid];
            const float val = fast_tanh(tot) + NOISEC * (nu - 0.5f);
            const unsigned long long pk =
                ((unsigned long long)(unsigned)t << 32) |
                (unsigned long long)__float_as_uint(val);
            __hip_atomic_store(slots + (size_t)(t & 1) * N_RES + row0 + tid, pk,
                               __ATOMIC_RELAXED, __HIP_MEMORY_SCOPE_AGENT);
            if (t == T_STEPS - 1) d_out[32 + row0 + tid] = val;
        }
        // no second barrier: red[] double-buffered by t&1; the next write to
        // this parity is behind the t+1 barrier, after wave0's read.
    }

    // ---- epilogue: block 0 computes readout = out_w @ s_final + out_b ----
    if (blk == 0) {
        const unsigned long long* sf = slots + (size_t)((T_STEPS - 1) & 1) * N_RES;
        const int r2 = tid >> 3, j2 = tid & 7;     // 32 rows x 8 lanes
        const unsigned need = (unsigned)(T_STEPS - 1);
        float acc = 0.f;
        for (int c0 = 0; c0 < N_RES / 8; c0 += 8) { // 256 cols/lane, 8 at a time
            const unsigned long long* p = sf + j2 * (N_RES / 8) + c0;
            unsigned long long vv[8];
            #pragma unroll
            for (int i = 0; i < 8; ++i)
                vv[i] = __hip_atomic_load(p + i, __ATOMIC_RELAXED, __HIP_MEMORY_SCOPE_AGENT);
            for (;;) {
                unsigned mn = 0xffffffffu;
                #pragma unroll
                for (int i = 0; i < 8; ++i) {
                    const unsigned tg = (unsigned)(vv[i] >> 32);
                    mn = (tg < mn) ? tg : mn;
                }
                if (mn >= need) break;
                __builtin_amdgcn_s_sleep(1);
                #pragma unroll
                for (int i = 0; i < 8; ++i)
                    if ((unsigned)(vv[i] >> 32) < need)
                        vv[i] = __hip_atomic_load(p + i, __ATOMIC_RELAXED, __HIP_MEMORY_SCOPE_AGENT);
            }
            #pragma unroll
            for (int i = 0; i < 8; ++i) {
                const float s = __uint_as_float((unsigned)(vv[i] & 0xffffffffu));
                acc = fmaf(out_w[r2 * N_RES + j2 * (N_RES / 8) + c0 + i], s, acc);
            }
        }
        #pragma unroll
        for (int m = 1; m < 8; m <<= 1) acc += __shfl_xor(acc, m, 64);
        if (j2 == 0) d_out[r2] = acc + out_b[r2];
    }
}

extern "C" void kernel_launch(void* const* d_in, const int* in_sizes, int n_in,
                              void* d_out, int out_size, void* d_ws, size_t ws_size,
                              hipStream_t stream) {
    const float* inputs  = (const float*)d_in[0];
    const float* outputs = (const float*)d_in[1];
    const float* w       = (const float*)d_in[2];
    const float* w_in    = (const float*)d_in[3];
    const float* w_feedb = (const float*)d_in[4];
    const float* out_w   = (const float*)d_in[5];
    const float* out_b   = (const float*)d_in[6];
    const float* noise_u = (const float*)d_in[7];
    unsigned long long* slots = (unsigned long long*)d_ws; // 2 x 2048 x 8B = 32 KB

    // re-init tags every call (d_ws is not re-poisoned between graph replays)
    esn_init<<<(2 * N_RES + NTHR - 1) / NTHR, NTHR, 0, stream>>>(slots);
    esn_run<<<NBLK, NTHR, 0, stream>>>(inputs, outputs, w, w_in, w_feedb,
                                       out_w, out_b, noise_u,
                                       (float*)d_out, slots);
}

// Round 8
// 11324.686 us; speedup vs baseline: 1.2499x; 1.2499x over previous
//
#include <hip/hip_runtime.h>

// ESN forward, teacher-forced: s[t] = tanh(w@s[t-1] + w_in@in[t] + w_fb@out[t-1]) + 1e-3*(nu[t]-0.5)
// Persistent kernel, 256 blocks x 256 threads, 8 rows/block, W in LDS (64KB).
//
// Round-8: replace per-word tagged polling with COUNTER-GATED exactly-once reads.
// Evidence across R2-R7: poll op rate is the poison (R7 3x rate => +75% dur;
// R3 8x store ops => +70%; R4 line-locality alone => only -5%). Per-line math:
// every state line had ~2048 chip-wide pollers at ~600cy cadence = 3.4 ops/cy/line
// at the IC coherence banks -- saturated, so samples went stale and stores
// queued behind reads. This round cuts poll ops ~250x:
//   - producers: 8 plain fp32 stores -> s_waitcnt vmcnt(0) (acked at IC) ->
//     ONE fetch_add to sub-counter [blk&7] (8 counters, 8 separate 64B lines).
//   - consumers: threads 0-7 spin on the 8 sub-counter lines (256 blocks x 8
//     = 2K poll ops/sweep chip-wide), __syncthreads broadcast, then each
//     thread reads its 8 state floats ONCE (agent-scope, guaranteed fresh).
//   - correctness: counters are monotonic (32 adds/sub-counter/step; target =
//     32*((t+1)>>1) for parity (t-1)&1, init pre-credits step 0). The 2-buffer
//     data reuse is race-free: A writes buf@t+1 only after its gate@t+1, which
//     requires B's publish@t, which is after B's reads@t-1 of the same lines.
// Kept from R5 (8.09ms best): W in LDS [rr][cc][tid][j] (0 bank conflicts),
// pre-gate ds_read prefetch + asm fence (lgkm rides out the vmcnt spin),
// strided column ownership, one finalize wave, fast tanh (exp2+rcp).

#define N_RES   2048
#define N_IN    64
#define N_OUT   32
#define T_STEPS 4096
#define NOISEC  0.001f
#define NBLK    256
#define NTHR    256
#define RPB     8     // rows per block
#define CPT     8     // state words (cols) per thread, stride NTHR

typedef float f32x4 __attribute__((ext_vector_type(4)));

__device__ __forceinline__ float fast_tanh(float x) {
    const float e = __builtin_amdgcn_exp2f(2.8853900818f * x);
    return fmaf(-2.f, __builtin_amdgcn_rcpf(e + 1.f), 1.f);
}

// ws layout: ull ctr[2][8][8] (1KB, sub-counters 64B apart), then float buf[2][2048]
__global__ void esn_init(unsigned long long* __restrict__ ctr,
                         float* __restrict__ buf) {
    const int i = blockIdx.x * blockDim.x + threadIdx.x;
    if (i < 128) {
        // parity-0 sub-counters pre-credited with step 0 (initial zero state)
        const unsigned long long v = (i < 64 && (i & 7) == 0) ? 32ull : 0ull;
        __hip_atomic_store(ctr + i, v, __ATOMIC_RELAXED, __HIP_MEMORY_SCOPE_AGENT);
    }
    if (i < 2 * N_RES)
        __hip_atomic_store(buf + i, 0.f, __ATOMIC_RELAXED, __HIP_MEMORY_SCOPE_AGENT);
}

__global__ __launch_bounds__(NTHR, 1)
void esn_run(const float* __restrict__ inputs,    // T x 64
             const float* __restrict__ outputs,   // T x 32
             const float* __restrict__ w,         // 2048 x 2048
             const float* __restrict__ w_in,      // 2048 x 64
             const float* __restrict__ w_feedb,   // 2048 x 32
             const float* __restrict__ out_w,     // 32 x 2048
             const float* __restrict__ out_b,     // 32
             const float* __restrict__ noise_u,   // T x 2048
             float* __restrict__ d_out,           // 32 + 2048
             unsigned long long* __restrict__ ctr,// 2 x 8 x 8
             float* __restrict__ buf) {           // 2 x 2048 state floats
    const int tid  = threadIdx.x;
    const int blk  = blockIdx.x;
    const int row0 = blk * RPB;
    const int wav  = tid >> 6;
    const int lan  = tid & 63;

    // [rr][cc][tid][j]: element (row = rr*4+j, col = cc*256+tid). 64KB.
    __shared__ float wlds[2 * 8 * NTHR * 4];
    __shared__ float red[2][4][RPB];

    // ---- one-time: stage my block's 8 W rows into LDS (coalesced reads) ----
    #pragma unroll
    for (int r = 0; r < RPB; ++r)
        #pragma unroll
        for (int cc = 0; cc < 8; ++cc) {
            const float v = w[(size_t)(row0 + r) * N_RES + cc * NTHR + tid];
            wlds[(((r >> 2) * 8 + cc) * NTHR + tid) * 4 + (r & 3)] = v;
        }
    // w_in / w_feedb: one virtual column per thread (tid<96)
    float wex[RPB];
    #pragma unroll
    for (int r = 0; r < RPB; ++r) {
        float v = 0.f;
        if (tid < N_IN)              v = w_in[(row0 + r) * N_IN + tid];
        else if (tid < N_IN + N_OUT) v = w_feedb[(row0 + r) * N_OUT + (tid - N_IN)];
        wex[r] = v;
    }
    __syncthreads();

    for (int t = 1; t < T_STEPS; ++t) {
        const int par = (t - 1) & 1;

        // ---- prefetch W fragment from LDS (state-independent) ----
        f32x4 wv[16];
        #pragma unroll
        for (int rr = 0; rr < 2; ++rr)
            #pragma unroll
            for (int cc = 0; cc < 8; ++cc)
                wv[rr * 8 + cc] = *reinterpret_cast<const f32x4*>(
                    &wlds[((rr * 8 + cc) * NTHR + tid) * 4]);

        // off-critical-path operands (overlap with the gate spin)
        float xv = 0.f;
        if (tid < N_IN)              xv = inputs[t * N_IN + tid];
        else if (tid < N_IN + N_OUT) xv = outputs[(t - 1) * N_OUT + (tid - N_IN)];
        float nu = 0.f;
        if (tid < RPB) nu = noise_u[(size_t)t * N_RES + row0 + tid];

        asm volatile("" ::: "memory");   // prefetches may not sink below

        // ---- gate: threads 0-7 spin on the 8 spread sub-counters ----
        const unsigned long long target = 32ull * (unsigned long long)((t + 1) >> 1);
        if (tid < 8) {
            const unsigned long long* cp = ctr + (size_t)(par * 8 + tid) * 8;
            while (__hip_atomic_load(cp, __ATOMIC_RELAXED, __HIP_MEMORY_SCOPE_AGENT) < target)
                __builtin_amdgcn_s_sleep(1);
        }
        __syncthreads();   // barrier 1: state@t-1 is globally visible

        // ---- bulk read my 8 state words, exactly once (agent scope) ----
        const float* sb = buf + (size_t)par * N_RES + tid;
        float sv[CPT];
        #pragma unroll
        for (int i = 0; i < CPT; ++i)
            sv[i] = __hip_atomic_load(sb + i * NTHR, __ATOMIC_RELAXED, __HIP_MEMORY_SCOPE_AGENT);

        // ---- partial dots: 8 rows x my 8 strided cols ----
        float acc[RPB];
        #pragma unroll
        for (int r = 0; r < RPB; ++r) acc[r] = 0.f;
        #pragma unroll
        for (int i = 0; i < CPT; ++i) {
            #pragma unroll
            for (int rr = 0; rr < 2; ++rr)
                #pragma unroll
                for (int j = 0; j < 4; ++j)
                    acc[rr * 4 + j] = fmaf(wv[rr * 8 + i][j], sv[i], acc[rr * 4 + j]);
        }
        #pragma unroll
        for (int r = 0; r < RPB; ++r) acc[r] = fmaf(wex[r], xv, acc[r]);

        // ---- wave reduce: halving exchange (1,2,4) then butterfly (8,16,32) ----
        {   const bool s = (lan & 1);
            #pragma unroll
            for (int r = 0; r < 4; ++r) {
                const float send = s ? acc[r] : acc[r + 4];
                const float got  = __shfl_xor(send, 1, 64);
                acc[r] = (s ? acc[r + 4] : acc[r]) + got;
            }
        }
        {   const bool s = (lan >> 1) & 1;
            #pragma unroll
            for (int r = 0; r < 2; ++r) {
                const float send = s ? acc[r] : acc[r + 2];
                const float got  = __shfl_xor(send, 2, 64);
                acc[r] = (s ? acc[r + 2] : acc[r]) + got;
            }
        }
        {   const bool s = (lan >> 2) & 1;
            const float send = s ? acc[0] : acc[1];
            const float got  = __shfl_xor(send, 4, 64);
            acc[0] = (s ? acc[1] : acc[0]) + got;
        }
        #pragma unroll
        for (int m = 8; m < 64; m <<= 1) acc[0] += __shfl_xor(acc[0], m, 64);
        if (lan < 8) {
            const int rb = 4 * (lan & 1) + 2 * ((lan >> 1) & 1) + ((lan >> 2) & 1);
            red[t & 1][wav][rb] = acc[0];
        }
        __syncthreads();   // barrier 2: red[] complete

        // ---- wave 0: finalize, publish values, ack, bump sub-counter ----
        if (tid < RPB) {
            const float tot = red[t & 1][0][tid] + red[t & 1][1][tid]
                            + red[t & 1][2][tid] + red[t & 1][3][tid];
            const float val = fast_tanh(tot) + NOISEC * (nu - 0.5f);
            __hip_atomic_store(buf + (size_t)(t & 1) * N_RES + row0 + tid, val,
                               __ATOMIC_RELAXED, __HIP_MEMORY_SCOPE_AGENT);
            if (t == T_STEPS - 1) d_out[32 + row0 + tid] = val;
        }
        if (wav == 0) {
            // wave-wide: wait the 8 lanes' stores to be acked at the
            // coherence point before signaling readiness
            asm volatile("s_waitcnt vmcnt(0)" ::: "memory");
            if (tid == 0)
                __hip_atomic_fetch_add(ctr + (size_t)((t & 1) * 8 + (blk & 7)) * 8,
                                       1ull, __ATOMIC_RELAXED, __HIP_MEMORY_SCOPE_AGENT);
        }
        // red[] WAR across steps: double-buffered by t&1; the next write to
        // this parity is two barriers away.
    }

    // ---- epilogue: block 0 computes readout = out_w @ s_final + out_b ----
    if (blk == 0) {
        const unsigned long long target = 32ull * 2048ull;  // all steps of parity 1
        if (tid < 8) {
            const unsigned long long* cp = ctr + (size_t)(1 * 8 + tid) * 8;
            while (__hip_atomic_load(cp, __ATOMIC_RELAXED, __HIP_MEMORY_SCOPE_AGENT) < target)
                __builtin_amdgcn_s_sleep(1);
        }
        __syncthreads();
        const float* sf = buf + N_RES;                 // parity of step 4095 = 1
        const int r2 = tid >> 3, j2 = tid & 7;         // 32 rows x 8 lanes
        float acc = 0.f;
        for (int c = j2; c < N_RES; c += 8) {
            const float s = __hip_atomic_load(sf + c, __ATOMIC_RELAXED, __HIP_MEMORY_SCOPE_AGENT);
            acc = fmaf(out_w[r2 * N_RES + c], s, acc);
        }
        #pragma unroll
        for (int m = 1; m < 8; m <<= 1) acc += __shfl_xor(acc, m, 64);
        if (j2 == 0) d_out[r2] = acc + out_b[r2];
    }
}

extern "C" void kernel_launch(void* const* d_in, const int* in_sizes, int n_in,
                              void* d_out, int out_size, void* d_ws, size_t ws_size,
                              hipStream_t stream) {
    const float* inputs  = (const float*)d_in[0];
    const float* outputs = (const float*)d_in[1];
    const float* w       = (const float*)d_in[2];
    const float* w_in    = (const float*)d_in[3];
    const float* w_feedb = (const float*)d_in[4];
    const float* out_w   = (const float*)d_in[5];
    const float* out_b   = (const float*)d_in[6];
    const float* noise_u = (const float*)d_in[7];

    unsigned long long* ctr = (unsigned long long*)d_ws;          // 2*8*8 ull = 1KB
    float* buf = (float*)((char*)d_ws + 1024);                    // 2*2048 f32 = 16KB

    // re-init every call (d_ws is not re-poisoned between graph replays;
    // counters are monotonic within a run and must restart each call)
    esn_init<<<16, NTHR, 0, stream>>>(ctr, buf);
    esn_run<<<NBLK, NTHR, 0, stream>>>(inputs, outputs, w, w_in, w_feedb,
                                       out_w, out_b, noise_u,
                                       (float*)d_out, ctr, buf);
}